// Round 9
// baseline (103.155 us; speedup 1.0000x reference)
//
#include <hip/hip_runtime.h>
#include <math.h>

#define NN 512
#define CC 32
#define EPSF 1e-8f
#define WS 40   // shorts per LDS row

typedef __attribute__((ext_vector_type(8))) short bf16x8;
typedef __attribute__((ext_vector_type(4))) float f32x4;

// fp32 -> bf16 bits, round-to-nearest-even
__device__ __forceinline__ short f2bf(float f) {
    unsigned u = __float_as_uint(f);
    u += 0x7fffu + ((u >> 16) & 1u);
    return (short)(u >> 16);
}

// Stage filter F's two 32x32 weight matrices as bf16 into LDS (compile-time F).
#define STAGE_F(F, W1P, W2P)                                                   \
    {                                                                          \
        const int n0 = tid >> 5, k0 = tid & 31;                                \
        wlds[(((F) * 2 + 0) * 32 + n0) * WS + k0]      = f2bf((W1P)[tid]);     \
        wlds[(((F) * 2 + 0) * 32 + n0 + 16) * WS + k0] = f2bf((W1P)[tid+512]); \
        wlds[(((F) * 2 + 1) * 32 + n0) * WS + k0]      = f2bf((W2P)[tid]);     \
        wlds[(((F) * 2 + 1) * 32 + n0 + 16) * WS + k0] = f2bf((W2P)[tid+512]); \
    }

// One radial MLP for 16 pairs; layer1 full hidden (2 MFMA), layer2 only this
// wave's 16-channel half (1 MFMA). Result R[rr] = rad[p=4q+rr][cw].
#define MLP3(WOFF, B1L, B1H, B2V, R)                                               \
    {                                                                              \
        const bf16x8 w1loM = *(const bf16x8*)&wlds[(WOFF) + ln * WS + q * 8];      \
        const bf16x8 w1hiM = *(const bf16x8*)&wlds[(WOFF) + (16 + ln) * WS + q * 8]; \
        f32x4 d0M = { (B1L), (B1L), (B1L), (B1L) };                                \
        f32x4 d1M = { (B1H), (B1H), (B1H), (B1H) };                                \
        d0M = __builtin_amdgcn_mfma_f32_16x16x32_bf16(rbfF, w1loM, d0M, 0, 0, 0);  \
        d1M = __builtin_amdgcn_mfma_f32_16x16x32_bf16(rbfF, w1hiM, d1M, 0, 0, 0);  \
        hlds[w][(q * 4 + 0) * WS + ln]      = f2bf(fmaxf(d0M[0], 0.f));            \
        hlds[w][(q * 4 + 1) * WS + ln]      = f2bf(fmaxf(d0M[1], 0.f));            \
        hlds[w][(q * 4 + 2) * WS + ln]      = f2bf(fmaxf(d0M[2], 0.f));            \
        hlds[w][(q * 4 + 3) * WS + ln]      = f2bf(fmaxf(d0M[3], 0.f));            \
        hlds[w][(q * 4 + 0) * WS + 16 + ln] = f2bf(fmaxf(d1M[0], 0.f));            \
        hlds[w][(q * 4 + 1) * WS + 16 + ln] = f2bf(fmaxf(d1M[1], 0.f));            \
        hlds[w][(q * 4 + 2) * WS + 16 + ln] = f2bf(fmaxf(d1M[2], 0.f));            \
        hlds[w][(q * 4 + 3) * WS + 16 + ln] = f2bf(fmaxf(d1M[3], 0.f));            \
        const bf16x8 hFM = *(const bf16x8*)&hlds[w][ln * WS + q * 8];              \
        const bf16x8 w2M = *(const bf16x8*)&wlds[(WOFF) + (32 + ch0 + ln) * WS + q * 8]; \
        f32x4 eM = { (B2V), (B2V), (B2V), (B2V) };                                 \
        R = __builtin_amdgcn_mfma_f32_16x16x32_bf16(hFM, w2M, eM, 0, 0, 0);        \
    }

// Merged aggregation for pair slot rr: all 5 filters, deduped loads.
#define AGGM(RR)                                                               \
    {                                                                          \
        const int bA = b0 + q * 4 + (RR);                                      \
        const f32x4 gA = *(const f32x4*)&geomall[bA][0];                       \
        const f32x4 gB = *(const f32x4*)&geomall[bA][4];                       \
        const float i0A = in0[bA * CC + cw];                                   \
        const float* i1A = in1 + (bA * CC + cw) * 3;                           \
        const float x1A = i1A[0], y1A = i1A[1], z1A = i1A[2];                  \
        const float* i2A = in2 + (bA * CC + cw) * 5;                           \
        const float p0A = i2A[0], p1A = i2A[1], p2A = i2A[2];                  \
        const float p3A = i2A[3], p4A = i2A[4];                                \
        const float s0A = rF0[(RR)];                                           \
        a0  = fmaf(s0A, i0A, a0);                                              \
        a5  = fmaf(s0A, x1A, a5);                                              \
        a6  = fmaf(s0A, y1A, a6);                                              \
        a7  = fmaf(s0A, z1A, a7);                                              \
        a16 = fmaf(s0A, p0A, a16);                                             \
        a17 = fmaf(s0A, p1A, a17);                                             \
        a18 = fmaf(s0A, p2A, a18);                                             \
        a19 = fmaf(s0A, p3A, a19);                                             \
        a20 = fmaf(s0A, p4A, a20);                                             \
        const float t1A = rF1[(RR)] * i0A;                                     \
        a2  = fmaf(t1A, gA[0], a2);                                            \
        a3  = fmaf(t1A, gA[1], a3);                                            \
        a4  = fmaf(t1A, gA[2], a4);                                            \
        const float t2A = rF2[(RR)] * i0A;                                     \
        a11 = fmaf(t2A, gA[3], a11);                                           \
        a12 = fmaf(t2A, gB[0], a12);                                           \
        a13 = fmaf(t2A, gB[1], a13);                                           \
        a14 = fmaf(t2A, gB[2], a14);                                           \
        a15 = fmaf(t2A, gB[3], a15);                                           \
        const float dtA = fmaf(gA[2], z1A, fmaf(gA[1], y1A, gA[0] * x1A));     \
        a1  = fmaf(rF3[(RR)], dtA, a1);                                        \
        const float cxA = fmaf(gA[1], z1A, -(gA[2] * y1A));                    \
        const float cyA = fmaf(gA[2], x1A, -(gA[0] * z1A));                    \
        const float czA = fmaf(gA[0], y1A, -(gA[1] * x1A));                    \
        a8  = fmaf(rF4[(RR)], cxA, a8);                                        \
        a9  = fmaf(rF4[(RR)], cyA, a9);                                        \
        a10 = fmaf(rF4[(RR)], czA, a10);                                       \
    }

#define RED(CMP, V)                                                            \
    {                                                                          \
        float vR = (V);                                                        \
        vR += __shfl_down(vR, 32);                                             \
        vR += __shfl_down(vR, 16);                                             \
        if (lane < 16) red[(w * 21 + (CMP)) * 16 + ln] = vR;                   \
    }

__global__ __launch_bounds__(512, 4) void tfn_mfma(
    const float* __restrict__ in0,   // [N,C,1]
    const float* __restrict__ in1,   // [N,C,3]
    const float* __restrict__ in2,   // [N,C,5]
    const float* __restrict__ rbf,   // [N,N,32]
    const float* __restrict__ rij,   // [N,N,3]
    const float* __restrict__ w1_0, const float* __restrict__ b1_0,
    const float* __restrict__ w2_0, const float* __restrict__ b2_0,
    const float* __restrict__ w1_1, const float* __restrict__ b1_1,
    const float* __restrict__ w2_1, const float* __restrict__ b2_1,
    const float* __restrict__ w1_2, const float* __restrict__ b1_2,
    const float* __restrict__ w2_2, const float* __restrict__ b2_2,
    const float* __restrict__ w1_3, const float* __restrict__ b1_3,
    const float* __restrict__ w2_3, const float* __restrict__ b2_3,
    const float* __restrict__ w1_4, const float* __restrict__ b1_4,
    const float* __restrict__ w2_4, const float* __restrict__ b2_4,
    float* __restrict__ out)
{
    const int a    = blockIdx.x;
    const int tid  = threadIdx.x;
    const int w    = tid >> 6;     // wave 0..7 = (b-range pair) * 2 + channel-half
    const int lane = tid & 63;
    const int q    = lane >> 4;
    const int ln   = lane & 15;
    const int ch0  = (w & 1) * 16; // this wave's channel-half base
    const int cw   = ch0 + ln;     // this lane's channel

    __shared__ short wlds[5 * 2 * 32 * WS];  // 25600 B; aliased as `red` later
    __shared__ short hlds[8][16 * WS];       // 10240 B per-wave h transpose tile
    __shared__ float geomall[NN][8];         // 16384 B: all b's geometry (mask folded)

    STAGE_F(0, w1_0, w2_0)
    STAGE_F(1, w1_1, w2_1)
    STAGE_F(2, w1_2, w2_2)
    STAGE_F(3, w1_3, w2_3)
    STAGE_F(4, w1_4, w2_4)

    const size_t rowbase = (size_t)a * NN;
    const float Y2C = 0.28867513459481287f;  // 1/(2*sqrt(3))

    // ---- geometry for ALL 512 b's, one thread each (no divergence) ----
    {
        const float* rp = rij + (rowbase + tid) * 3;
        const float x = rp[0], y = rp[1], z = rp[2];
        const float d2 = x * x + y * y + z * z;
        const float d  = sqrtf(d2);
        const float m  = (d >= EPSF) ? 1.f : 0.f;
        const float inv = m / (d + EPSF);
        const float ir2 = m / fmaxf(d2, EPSF);
        f32x4 gA = { x * inv, y * inv, z * inv, x * y * ir2 };
        f32x4 gB = { y * z * ir2, (2.f * z * z - x * x - y * y) * (ir2 * Y2C),
                     z * x * ir2, (x * x - y * y) * (ir2 * 0.5f) };
        *(f32x4*)&geomall[tid][0] = gA;
        *(f32x4*)&geomall[tid][4] = gB;
    }

    // layer-1 biases: full hidden (both halves); layer-2 bias: own half only
    const float b1lo0 = b1_0[ln], b1hi0 = b1_0[16 + ln], b2v0 = b2_0[cw];
    const float b1lo1 = b1_1[ln], b1hi1 = b1_1[16 + ln], b2v1 = b2_1[cw];
    const float b1lo2 = b1_2[ln], b1hi2 = b1_2[16 + ln], b2v2 = b2_2[cw];
    const float b1lo3 = b1_3[ln], b1hi3 = b1_3[16 + ln], b2v3 = b2_3[cw];
    const float b1lo4 = b1_4[ln], b1hi4 = b1_4[16 + ln], b2v4 = b2_4[cw];
    __syncthreads();

    // 21 named scalar accumulators
    float a0 = 0.f, a1 = 0.f, a2 = 0.f, a3 = 0.f, a4 = 0.f, a5 = 0.f, a6 = 0.f;
    float a7 = 0.f, a8 = 0.f, a9 = 0.f, a10 = 0.f, a11 = 0.f, a12 = 0.f, a13 = 0.f;
    float a14 = 0.f, a15 = 0.f, a16 = 0.f, a17 = 0.f, a18 = 0.f, a19 = 0.f, a20 = 0.f;

    const int pairb = (w >> 1) * 128;        // this wave-pair's b range

    // software prefetch of the first rbf fragment
    const float* rbase = rbf + (rowbase + pairb + ln) * 32 + q * 8;
    f32x4 curA = *(const f32x4*)rbase;
    f32x4 curB = *(const f32x4*)(rbase + 4);

    #pragma unroll 1
    for (int t = 0; t < 8; ++t) {
        const int b0 = pairb + t * 16;

        // convert current rbf fragment, then prefetch next tile's
        bf16x8 rbfF;
        rbfF[0] = f2bf(curA[0]); rbfF[1] = f2bf(curA[1]);
        rbfF[2] = f2bf(curA[2]); rbfF[3] = f2bf(curA[3]);
        rbfF[4] = f2bf(curB[0]); rbfF[5] = f2bf(curB[1]);
        rbfF[6] = f2bf(curB[2]); rbfF[7] = f2bf(curB[3]);
        if (t < 7) {
            curA = *(const f32x4*)(rbase + (t + 1) * 512);
            curB = *(const f32x4*)(rbase + (t + 1) * 512 + 4);
        }

        f32x4 rF0, rF1, rF2, rF3, rF4;
        MLP3(0 * 64 * WS, b1lo0, b1hi0, b2v0, rF0)
        MLP3(1 * 64 * WS, b1lo1, b1hi1, b2v1, rF1)
        MLP3(2 * 64 * WS, b1lo2, b1hi2, b2v2, rF2)
        MLP3(3 * 64 * WS, b1lo3, b1hi3, b2v3, rF3)
        MLP3(4 * 64 * WS, b1lo4, b1hi4, b2v4, rF4)

        AGGM(0) AGGM(1) AGGM(2) AGGM(3)

        __builtin_amdgcn_sched_barrier(0);
    }

    // ---- reduce over q within wave, then over the 4 b-range pairs via LDS ----
    __syncthreads();                       // all waves done reading wlds
    float* red = (float*)wlds;             // [8][21][16] = 10752 B <= 25600 B
    RED(0,  a0)  RED(1,  a1)  RED(2,  a2)  RED(3,  a3)  RED(4,  a4)
    RED(5,  a5)  RED(6,  a6)  RED(7,  a7)  RED(8,  a8)  RED(9,  a9)
    RED(10, a10) RED(11, a11) RED(12, a12) RED(13, a13) RED(14, a14)
    RED(15, a15) RED(16, a16) RED(17, a17) RED(18, a18) RED(19, a19)
    RED(20, a20)
    __syncthreads();

    const int NC = NN * CC;
    for (int e = tid; e < 21 * 32; e += 512) {
        const int cmp = e >> 5, c = e & 31;
        const int hh = c >> 4, l2 = c & 15;
        float s = 0.f;
        #pragma unroll
        for (int p = 0; p < 4; ++p)
            s += red[((p * 2 + hh) * 21 + cmp) * 16 + l2];
        int idx;
        if (cmp == 0)       idx = a * CC + c;                                       // o0_s
        else if (cmp == 1)  idx = NC + a * CC + c;                                  // o0_b
        else if (cmp < 5)   idx = 2 * NC + (a * CC + c) * 3 + (cmp - 2);            // o1_a
        else if (cmp < 8)   idx = 2 * NC + 3 * NC + (a * CC + c) * 3 + (cmp - 5);   // o1_s
        else if (cmp < 11)  idx = 2 * NC + 6 * NC + (a * CC + c) * 3 + (cmp - 8);   // o1_c
        else if (cmp < 16)  idx = 11 * NC + (a * CC + c) * 5 + (cmp - 11);          // o2_a
        else                idx = 11 * NC + 5 * NC + (a * CC + c) * 5 + (cmp - 16); // o2_s
        out[idx] = s;
    }
}

extern "C" void kernel_launch(void* const* d_in, const int* in_sizes, int n_in,
                              void* d_out, int out_size, void* d_ws, size_t ws_size,
                              hipStream_t stream) {
    const float* in0 = (const float*)d_in[0];
    const float* in1 = (const float*)d_in[1];
    const float* in2 = (const float*)d_in[2];
    const float* rbf = (const float*)d_in[3];
    const float* rij = (const float*)d_in[4];

    hipLaunchKernelGGL(tfn_mfma, dim3(NN), dim3(512), 0, stream,
                       in0, in1, in2, rbf, rij,
                       (const float*)d_in[5],  (const float*)d_in[6],
                       (const float*)d_in[7],  (const float*)d_in[8],
                       (const float*)d_in[9],  (const float*)d_in[10],
                       (const float*)d_in[11], (const float*)d_in[12],
                       (const float*)d_in[13], (const float*)d_in[14],
                       (const float*)d_in[15], (const float*)d_in[16],
                       (const float*)d_in[17], (const float*)d_in[18],
                       (const float*)d_in[19], (const float*)d_in[20],
                       (const float*)d_in[21], (const float*)d_in[22],
                       (const float*)d_in[23], (const float*)d_in[24],
                       (float*)d_out);
}

// Round 10
// 42.093 us; speedup vs baseline: 2.4507x; 2.4507x over previous
//
#include <hip/hip_runtime.h>
#include <math.h>

#define NN 512
#define CC 32
#define EPSF 1e-8f
#define WS 40   // shorts per LDS row

typedef __attribute__((ext_vector_type(8))) short bf16x8;
typedef __attribute__((ext_vector_type(4))) float f32x4;

// fp32 -> bf16 bits, round-to-nearest-even
__device__ __forceinline__ short f2bf(float f) {
    unsigned u = __float_as_uint(f);
    u += 0x7fffu + ((u >> 16) & 1u);
    return (short)(u >> 16);
}

// Stage filter F's two 32x32 weight matrices as bf16 into LDS (compile-time F).
#define STAGE_F(F, W1P, W2P)                                                   \
    {                                                                          \
        const int n0 = tid >> 5, k0 = tid & 31;                                \
        wlds[(((F) * 2 + 0) * 32 + n0) * WS + k0]      = f2bf((W1P)[tid]);     \
        wlds[(((F) * 2 + 0) * 32 + n0 + 16) * WS + k0] = f2bf((W1P)[tid+512]); \
        wlds[(((F) * 2 + 1) * 32 + n0) * WS + k0]      = f2bf((W2P)[tid]);     \
        wlds[(((F) * 2 + 1) * 32 + n0 + 16) * WS + k0] = f2bf((W2P)[tid+512]); \
    }

// One radial MLP for 16 pairs; layer1 full hidden (2 MFMA), layer2 only this
// wave's 16-channel half (1 MFMA). Result R[rr] = rad[p=4q+rr][cw].
#define MLP3(WOFF, B1L, B1H, B2V, R)                                               \
    {                                                                              \
        const bf16x8 w1loM = *(const bf16x8*)&wlds[(WOFF) + ln * WS + q * 8];      \
        const bf16x8 w1hiM = *(const bf16x8*)&wlds[(WOFF) + (16 + ln) * WS + q * 8]; \
        f32x4 d0M = { (B1L), (B1L), (B1L), (B1L) };                                \
        f32x4 d1M = { (B1H), (B1H), (B1H), (B1H) };                                \
        d0M = __builtin_amdgcn_mfma_f32_16x16x32_bf16(rbfF, w1loM, d0M, 0, 0, 0);  \
        d1M = __builtin_amdgcn_mfma_f32_16x16x32_bf16(rbfF, w1hiM, d1M, 0, 0, 0);  \
        hlds[w][(q * 4 + 0) * WS + ln]      = f2bf(fmaxf(d0M[0], 0.f));            \
        hlds[w][(q * 4 + 1) * WS + ln]      = f2bf(fmaxf(d0M[1], 0.f));            \
        hlds[w][(q * 4 + 2) * WS + ln]      = f2bf(fmaxf(d0M[2], 0.f));            \
        hlds[w][(q * 4 + 3) * WS + ln]      = f2bf(fmaxf(d0M[3], 0.f));            \
        hlds[w][(q * 4 + 0) * WS + 16 + ln] = f2bf(fmaxf(d1M[0], 0.f));            \
        hlds[w][(q * 4 + 1) * WS + 16 + ln] = f2bf(fmaxf(d1M[1], 0.f));            \
        hlds[w][(q * 4 + 2) * WS + 16 + ln] = f2bf(fmaxf(d1M[2], 0.f));            \
        hlds[w][(q * 4 + 3) * WS + 16 + ln] = f2bf(fmaxf(d1M[3], 0.f));            \
        const bf16x8 hFM = *(const bf16x8*)&hlds[w][ln * WS + q * 8];              \
        const bf16x8 w2M = *(const bf16x8*)&wlds[(WOFF) + (32 + ch0 + ln) * WS + q * 8]; \
        f32x4 eM = { (B2V), (B2V), (B2V), (B2V) };                                 \
        R = __builtin_amdgcn_mfma_f32_16x16x32_bf16(hFM, w2M, eM, 0, 0, 0);        \
    }

// Merged aggregation for pair slot rr: all 5 filters, deduped loads.
#define AGGM(RR)                                                               \
    {                                                                          \
        const int bA = b0 + q * 4 + (RR);                                      \
        const f32x4 gA = *(const f32x4*)&geomall[bA][0];                       \
        const f32x4 gB = *(const f32x4*)&geomall[bA][4];                       \
        const float i0A = in0[bA * CC + cw];                                   \
        const float* i1A = in1 + (bA * CC + cw) * 3;                           \
        const float x1A = i1A[0], y1A = i1A[1], z1A = i1A[2];                  \
        const float* i2A = in2 + (bA * CC + cw) * 5;                           \
        const float p0A = i2A[0], p1A = i2A[1], p2A = i2A[2];                  \
        const float p3A = i2A[3], p4A = i2A[4];                                \
        const float s0A = rF0[(RR)];                                           \
        a0  = fmaf(s0A, i0A, a0);                                              \
        a5  = fmaf(s0A, x1A, a5);                                              \
        a6  = fmaf(s0A, y1A, a6);                                              \
        a7  = fmaf(s0A, z1A, a7);                                              \
        a16 = fmaf(s0A, p0A, a16);                                             \
        a17 = fmaf(s0A, p1A, a17);                                             \
        a18 = fmaf(s0A, p2A, a18);                                             \
        a19 = fmaf(s0A, p3A, a19);                                             \
        a20 = fmaf(s0A, p4A, a20);                                             \
        const float t1A = rF1[(RR)] * i0A;                                     \
        a2  = fmaf(t1A, gA[0], a2);                                            \
        a3  = fmaf(t1A, gA[1], a3);                                            \
        a4  = fmaf(t1A, gA[2], a4);                                            \
        const float t2A = rF2[(RR)] * i0A;                                     \
        a11 = fmaf(t2A, gA[3], a11);                                           \
        a12 = fmaf(t2A, gB[0], a12);                                           \
        a13 = fmaf(t2A, gB[1], a13);                                           \
        a14 = fmaf(t2A, gB[2], a14);                                           \
        a15 = fmaf(t2A, gB[3], a15);                                           \
        const float dtA = fmaf(gA[2], z1A, fmaf(gA[1], y1A, gA[0] * x1A));     \
        a1  = fmaf(rF3[(RR)], dtA, a1);                                        \
        const float cxA = fmaf(gA[1], z1A, -(gA[2] * y1A));                    \
        const float cyA = fmaf(gA[2], x1A, -(gA[0] * z1A));                    \
        const float czA = fmaf(gA[0], y1A, -(gA[1] * x1A));                    \
        a8  = fmaf(rF4[(RR)], cxA, a8);                                        \
        a9  = fmaf(rF4[(RR)], cyA, a9);                                        \
        a10 = fmaf(rF4[(RR)], czA, a10);                                       \
    }

#define RED(CMP, V)                                                            \
    {                                                                          \
        float vR = (V);                                                        \
        vR += __shfl_down(vR, 32);                                             \
        vR += __shfl_down(vR, 16);                                             \
        if (lane < 16) red[(w * 21 + (CMP)) * 16 + ln] = vR;                   \
    }

__global__ __launch_bounds__(512, 2) void tfn_mfma(
    const float* __restrict__ in0,   // [N,C,1]
    const float* __restrict__ in1,   // [N,C,3]
    const float* __restrict__ in2,   // [N,C,5]
    const float* __restrict__ rbf,   // [N,N,32]
    const float* __restrict__ rij,   // [N,N,3]
    const float* __restrict__ w1_0, const float* __restrict__ b1_0,
    const float* __restrict__ w2_0, const float* __restrict__ b2_0,
    const float* __restrict__ w1_1, const float* __restrict__ b1_1,
    const float* __restrict__ w2_1, const float* __restrict__ b2_1,
    const float* __restrict__ w1_2, const float* __restrict__ b1_2,
    const float* __restrict__ w2_2, const float* __restrict__ b2_2,
    const float* __restrict__ w1_3, const float* __restrict__ b1_3,
    const float* __restrict__ w2_3, const float* __restrict__ b2_3,
    const float* __restrict__ w1_4, const float* __restrict__ b1_4,
    const float* __restrict__ w2_4, const float* __restrict__ b2_4,
    float* __restrict__ out)
{
    const int a    = blockIdx.x;
    const int tid  = threadIdx.x;
    const int w    = tid >> 6;     // wave 0..7 = (b-range pair) * 2 + channel-half
    const int lane = tid & 63;
    const int q    = lane >> 4;
    const int ln   = lane & 15;
    const int ch0  = (w & 1) * 16; // this wave's channel-half base
    const int cw   = ch0 + ln;     // this lane's channel

    __shared__ short wlds[5 * 2 * 32 * WS];  // 25600 B; aliased as `red` later
    __shared__ short hlds[8][16 * WS];       // 10240 B per-wave h transpose tile
    __shared__ float geomall[NN][8];         // 16384 B: all b's geometry (mask folded)

    STAGE_F(0, w1_0, w2_0)
    STAGE_F(1, w1_1, w2_1)
    STAGE_F(2, w1_2, w2_2)
    STAGE_F(3, w1_3, w2_3)
    STAGE_F(4, w1_4, w2_4)

    const size_t rowbase = (size_t)a * NN;
    const float Y2C = 0.28867513459481287f;  // 1/(2*sqrt(3))

    // ---- geometry for ALL 512 b's, one thread each (no divergence) ----
    {
        const float* rp = rij + (rowbase + tid) * 3;
        const float x = rp[0], y = rp[1], z = rp[2];
        const float d2 = x * x + y * y + z * z;
        const float d  = sqrtf(d2);
        const float m  = (d >= EPSF) ? 1.f : 0.f;
        const float inv = m / (d + EPSF);
        const float ir2 = m / fmaxf(d2, EPSF);
        f32x4 gA = { x * inv, y * inv, z * inv, x * y * ir2 };
        f32x4 gB = { y * z * ir2, (2.f * z * z - x * x - y * y) * (ir2 * Y2C),
                     z * x * ir2, (x * x - y * y) * (ir2 * 0.5f) };
        *(f32x4*)&geomall[tid][0] = gA;
        *(f32x4*)&geomall[tid][4] = gB;
    }

    // layer-1 biases: full hidden (both halves); layer-2 bias: own half only
    const float b1lo0 = b1_0[ln], b1hi0 = b1_0[16 + ln], b2v0 = b2_0[cw];
    const float b1lo1 = b1_1[ln], b1hi1 = b1_1[16 + ln], b2v1 = b2_1[cw];
    const float b1lo2 = b1_2[ln], b1hi2 = b1_2[16 + ln], b2v2 = b2_2[cw];
    const float b1lo3 = b1_3[ln], b1hi3 = b1_3[16 + ln], b2v3 = b2_3[cw];
    const float b1lo4 = b1_4[ln], b1hi4 = b1_4[16 + ln], b2v4 = b2_4[cw];
    __syncthreads();

    // 21 named scalar accumulators
    float a0 = 0.f, a1 = 0.f, a2 = 0.f, a3 = 0.f, a4 = 0.f, a5 = 0.f, a6 = 0.f;
    float a7 = 0.f, a8 = 0.f, a9 = 0.f, a10 = 0.f, a11 = 0.f, a12 = 0.f, a13 = 0.f;
    float a14 = 0.f, a15 = 0.f, a16 = 0.f, a17 = 0.f, a18 = 0.f, a19 = 0.f, a20 = 0.f;

    const int pairb = (w >> 1) * 128;        // this wave-pair's b range

    // software prefetch of the first rbf fragment
    const float* rbase = rbf + (rowbase + pairb + ln) * 32 + q * 8;
    f32x4 curA = *(const f32x4*)rbase;
    f32x4 curB = *(const f32x4*)(rbase + 4);

    #pragma unroll 1
    for (int t = 0; t < 8; ++t) {
        const int b0 = pairb + t * 16;

        // convert current rbf fragment, then prefetch next tile's
        bf16x8 rbfF;
        rbfF[0] = f2bf(curA[0]); rbfF[1] = f2bf(curA[1]);
        rbfF[2] = f2bf(curA[2]); rbfF[3] = f2bf(curA[3]);
        rbfF[4] = f2bf(curB[0]); rbfF[5] = f2bf(curB[1]);
        rbfF[6] = f2bf(curB[2]); rbfF[7] = f2bf(curB[3]);
        if (t < 7) {
            curA = *(const f32x4*)(rbase + (t + 1) * 512);
            curB = *(const f32x4*)(rbase + (t + 1) * 512 + 4);
        }

        f32x4 rF0, rF1, rF2, rF3, rF4;
        MLP3(0 * 64 * WS, b1lo0, b1hi0, b2v0, rF0)
        MLP3(1 * 64 * WS, b1lo1, b1hi1, b2v1, rF1)
        MLP3(2 * 64 * WS, b1lo2, b1hi2, b2v2, rF2)
        MLP3(3 * 64 * WS, b1lo3, b1hi3, b2v3, rF3)
        MLP3(4 * 64 * WS, b1lo4, b1hi4, b2v4, rF4)

        AGGM(0) AGGM(1) AGGM(2) AGGM(3)

        __builtin_amdgcn_sched_barrier(0);
    }

    // ---- reduce over q within wave, then over the 4 b-range pairs via LDS ----
    __syncthreads();                       // all waves done reading wlds
    float* red = (float*)wlds;             // [8][21][16] = 10752 B <= 25600 B
    RED(0,  a0)  RED(1,  a1)  RED(2,  a2)  RED(3,  a3)  RED(4,  a4)
    RED(5,  a5)  RED(6,  a6)  RED(7,  a7)  RED(8,  a8)  RED(9,  a9)
    RED(10, a10) RED(11, a11) RED(12, a12) RED(13, a13) RED(14, a14)
    RED(15, a15) RED(16, a16) RED(17, a17) RED(18, a18) RED(19, a19)
    RED(20, a20)
    __syncthreads();

    const int NC = NN * CC;
    for (int e = tid; e < 21 * 32; e += 512) {
        const int cmp = e >> 5, c = e & 31;
        const int hh = c >> 4, l2 = c & 15;
        float s = 0.f;
        #pragma unroll
        for (int p = 0; p < 4; ++p)
            s += red[((p * 2 + hh) * 21 + cmp) * 16 + l2];
        int idx;
        if (cmp == 0)       idx = a * CC + c;                                       // o0_s
        else if (cmp == 1)  idx = NC + a * CC + c;                                  // o0_b
        else if (cmp < 5)   idx = 2 * NC + (a * CC + c) * 3 + (cmp - 2);            // o1_a
        else if (cmp < 8)   idx = 2 * NC + 3 * NC + (a * CC + c) * 3 + (cmp - 5);   // o1_s
        else if (cmp < 11)  idx = 2 * NC + 6 * NC + (a * CC + c) * 3 + (cmp - 8);   // o1_c
        else if (cmp < 16)  idx = 11 * NC + (a * CC + c) * 5 + (cmp - 11);          // o2_a
        else                idx = 11 * NC + 5 * NC + (a * CC + c) * 5 + (cmp - 16); // o2_s
        out[idx] = s;
    }
}

extern "C" void kernel_launch(void* const* d_in, const int* in_sizes, int n_in,
                              void* d_out, int out_size, void* d_ws, size_t ws_size,
                              hipStream_t stream) {
    const float* in0 = (const float*)d_in[0];
    const float* in1 = (const float*)d_in[1];
    const float* in2 = (const float*)d_in[2];
    const float* rbf = (const float*)d_in[3];
    const float* rij = (const float*)d_in[4];

    hipLaunchKernelGGL(tfn_mfma, dim3(NN), dim3(512), 0, stream,
                       in0, in1, in2, rbf, rij,
                       (const float*)d_in[5],  (const float*)d_in[6],
                       (const float*)d_in[7],  (const float*)d_in[8],
                       (const float*)d_in[9],  (const float*)d_in[10],
                       (const float*)d_in[11], (const float*)d_in[12],
                       (const float*)d_in[13], (const float*)d_in[14],
                       (const float*)d_in[15], (const float*)d_in[16],
                       (const float*)d_in[17], (const float*)d_in[18],
                       (const float*)d_in[19], (const float*)d_in[20],
                       (const float*)d_in[21], (const float*)d_in[22],
                       (const float*)d_in[23], (const float*)d_in[24],
                       (float*)d_out);
}

// Round 12
// 40.461 us; speedup vs baseline: 2.5495x; 1.0403x over previous
//
#include <hip/hip_runtime.h>
#include <math.h>

#define NN 512
#define CC 32
#define EPSF 1e-8f
#define WS 40   // shorts per LDS row

typedef __attribute__((ext_vector_type(8))) short bf16x8;
typedef __attribute__((ext_vector_type(4))) float f32x4;

// fp32 -> bf16 bits, round-to-nearest-even (staging only)
__device__ __forceinline__ short f2bf(float f) {
    unsigned u = __float_as_uint(f);
    u += 0x7fffu + ((u >> 16) & 1u);
    return (short)(u >> 16);
}

// packed f32x2 -> bf16x2 (RTNE), 1 VALU op
__device__ __forceinline__ unsigned cvtpk(float lo, float hi) {
    unsigned r;
    asm("v_cvt_pk_bf16_f32 %0, %1, %2" : "=v"(r) : "v"(lo), "v"(hi));
    return r;
}

// Stage filter F's weights as bf16 into LDS (compile-time F).
// w1 stored plain: row n, col k.  w2 stored with k-axis permuted by perm()
// so layer-2's A-fragment is lane-local after the swapped layer-1 MFMA.
#define STAGE_F(F, W1P, W2P)                                                   \
    {                                                                          \
        wlds[(((F) * 2 + 0) * 32 + n0) * WS + k0]      = f2bf((W1P)[tid]);     \
        wlds[(((F) * 2 + 0) * 32 + n0 + 16) * WS + k0] = f2bf((W1P)[tid+512]); \
        wlds[(((F) * 2 + 1) * 32 + n0) * WS + k2]      = f2bf((W2P)[tid]);     \
        wlds[(((F) * 2 + 1) * 32 + n0 + 16) * WS + k2] = f2bf((W2P)[tid+512]); \
    }

// Radial MLP, transpose-free:
//  layer1 swapped operands: d = mfma(w1, rbf) -> lane(q,ln) = h[n][p=ln],
//    n in {4q+reg} (d0M) and {16+4q+reg} (d1M)
//  relu+cvt_pk packs those 8 values; under the k-permutation pi they ARE the
//  layer-2 A-frag h[p=ln][k'=8q+j] (w2 staged with matching permutation)
//  layer2: R[rr] = rad[p=4q+rr][cw]
#define MLP3S(WOFF, B1LO, B1HI, B2V, R)                                            \
    {                                                                              \
        const bf16x8 w1loM = *(const bf16x8*)&wlds[(WOFF) + ln * WS + q * 8];      \
        const bf16x8 w1hiM = *(const bf16x8*)&wlds[(WOFF) + (16 + ln) * WS + q * 8]; \
        f32x4 d0M = (B1LO);                                                        \
        f32x4 d1M = (B1HI);                                                        \
        d0M = __builtin_amdgcn_mfma_f32_16x16x32_bf16(w1loM, rbfF, d0M, 0, 0, 0);  \
        d1M = __builtin_amdgcn_mfma_f32_16x16x32_bf16(w1hiM, rbfF, d1M, 0, 0, 0);  \
        union { bf16x8 v; unsigned u[4]; } hu;                                     \
        hu.u[0] = cvtpk(fmaxf(d0M[0], 0.f), fmaxf(d0M[1], 0.f));                   \
        hu.u[1] = cvtpk(fmaxf(d0M[2], 0.f), fmaxf(d0M[3], 0.f));                   \
        hu.u[2] = cvtpk(fmaxf(d1M[0], 0.f), fmaxf(d1M[1], 0.f));                   \
        hu.u[3] = cvtpk(fmaxf(d1M[2], 0.f), fmaxf(d1M[3], 0.f));                   \
        const bf16x8 w2M = *(const bf16x8*)&wlds[(WOFF) + (32 + ch0 + ln) * WS + q * 8]; \
        f32x4 eM = { (B2V), (B2V), (B2V), (B2V) };                                 \
        R = __builtin_amdgcn_mfma_f32_16x16x32_bf16(hu.v, w2M, eM, 0, 0, 0);       \
    }

// Merged aggregation for pair slot rr: all 5 filters, deduped loads.
#define AGGM(RR)                                                               \
    {                                                                          \
        const int bA = b0 + q * 4 + (RR);                                      \
        const f32x4 gA = *(const f32x4*)&geomall[bA][0];                       \
        const f32x4 gB = *(const f32x4*)&geomall[bA][4];                       \
        const float i0A = in0[bA * CC + cw];                                   \
        const float* i1A = in1 + (bA * CC + cw) * 3;                           \
        const float x1A = i1A[0], y1A = i1A[1], z1A = i1A[2];                  \
        const float* i2A = in2 + (bA * CC + cw) * 5;                           \
        const float p0A = i2A[0], p1A = i2A[1], p2A = i2A[2];                  \
        const float p3A = i2A[3], p4A = i2A[4];                                \
        const float s0A = rF0[(RR)];                                           \
        a0  = fmaf(s0A, i0A, a0);                                              \
        a5  = fmaf(s0A, x1A, a5);                                              \
        a6  = fmaf(s0A, y1A, a6);                                              \
        a7  = fmaf(s0A, z1A, a7);                                              \
        a16 = fmaf(s0A, p0A, a16);                                             \
        a17 = fmaf(s0A, p1A, a17);                                             \
        a18 = fmaf(s0A, p2A, a18);                                             \
        a19 = fmaf(s0A, p3A, a19);                                             \
        a20 = fmaf(s0A, p4A, a20);                                             \
        const float t1A = rF1[(RR)] * i0A;                                     \
        a2  = fmaf(t1A, gA[0], a2);                                            \
        a3  = fmaf(t1A, gA[1], a3);                                            \
        a4  = fmaf(t1A, gA[2], a4);                                            \
        const float t2A = rF2[(RR)] * i0A;                                     \
        a11 = fmaf(t2A, gA[3], a11);                                           \
        a12 = fmaf(t2A, gB[0], a12);                                           \
        a13 = fmaf(t2A, gB[1], a13);                                           \
        a14 = fmaf(t2A, gB[2], a14);                                           \
        a15 = fmaf(t2A, gB[3], a15);                                           \
        const float dtA = fmaf(gA[2], z1A, fmaf(gA[1], y1A, gA[0] * x1A));     \
        a1  = fmaf(rF3[(RR)], dtA, a1);                                        \
        const float cxA = fmaf(gA[1], z1A, -(gA[2] * y1A));                    \
        const float cyA = fmaf(gA[2], x1A, -(gA[0] * z1A));                    \
        const float czA = fmaf(gA[0], y1A, -(gA[1] * x1A));                    \
        a8  = fmaf(rF4[(RR)], cxA, a8);                                        \
        a9  = fmaf(rF4[(RR)], cyA, a9);                                        \
        a10 = fmaf(rF4[(RR)], czA, a10);                                       \
    }

#define RED(CMP, V)                                                            \
    {                                                                          \
        float vR = (V);                                                        \
        vR += __shfl_down(vR, 32);                                             \
        vR += __shfl_down(vR, 16);                                             \
        if (lane < 16) red[(w * 21 + (CMP)) * 16 + ln] = vR;                   \
    }

__global__ __launch_bounds__(512, 2) void tfn_mfma(
    const float* __restrict__ in0,   // [N,C,1]
    const float* __restrict__ in1,   // [N,C,3]
    const float* __restrict__ in2,   // [N,C,5]
    const float* __restrict__ rbf,   // [N,N,32]
    const float* __restrict__ rij,   // [N,N,3]
    const float* __restrict__ w1_0, const float* __restrict__ b1_0,
    const float* __restrict__ w2_0, const float* __restrict__ b2_0,
    const float* __restrict__ w1_1, const float* __restrict__ b1_1,
    const float* __restrict__ w2_1, const float* __restrict__ b2_1,
    const float* __restrict__ w1_2, const float* __restrict__ b1_2,
    const float* __restrict__ w2_2, const float* __restrict__ b2_2,
    const float* __restrict__ w1_3, const float* __restrict__ b1_3,
    const float* __restrict__ w2_3, const float* __restrict__ b2_3,
    const float* __restrict__ w1_4, const float* __restrict__ b1_4,
    const float* __restrict__ w2_4, const float* __restrict__ b2_4,
    float* __restrict__ out)
{
    const int a    = blockIdx.x;
    const int tid  = threadIdx.x;
    const int w    = tid >> 6;     // wave 0..7 = (b-range pair) * 2 + channel-half
    const int lane = tid & 63;
    const int q    = lane >> 4;
    const int ln   = lane & 15;
    const int ch0  = (w & 1) * 16; // this wave's channel-half base
    const int cw   = ch0 + ln;     // this lane's channel

    __shared__ short wlds[5 * 2 * 32 * WS];  // 25600 B; aliased as `red` later
    __shared__ float geomall[NN][8];         // 16384 B: all b's geometry (mask folded)

    // staging indices; k2 = perm(k0): n-axis permutation for layer-2 weights
    const int n0 = tid >> 5, k0 = tid & 31;
    const int k2 = (k0 < 16) ? ((k0 >> 2) * 8 + (k0 & 3))
                             : (((k0 - 16) >> 2) * 8 + 4 + ((k0 - 16) & 3));

    STAGE_F(0, w1_0, w2_0)
    STAGE_F(1, w1_1, w2_1)
    STAGE_F(2, w1_2, w2_2)
    STAGE_F(3, w1_3, w2_3)
    STAGE_F(4, w1_4, w2_4)

    const size_t rowbase = (size_t)a * NN;
    const float Y2C = 0.28867513459481287f;  // 1/(2*sqrt(3))

    // ---- geometry for ALL 512 b's, one thread each (no divergence) ----
    {
        const float* rp = rij + (rowbase + tid) * 3;
        const float x = rp[0], y = rp[1], z = rp[2];
        const float d2 = x * x + y * y + z * z;
        const float d  = sqrtf(d2);
        const float m  = (d >= EPSF) ? 1.f : 0.f;
        const float inv = m / (d + EPSF);
        const float ir2 = m / fmaxf(d2, EPSF);
        f32x4 gA = { x * inv, y * inv, z * inv, x * y * ir2 };
        f32x4 gB = { y * z * ir2, (2.f * z * z - x * x - y * y) * (ir2 * Y2C),
                     z * x * ir2, (x * x - y * y) * (ir2 * 0.5f) };
        *(f32x4*)&geomall[tid][0] = gA;
        *(f32x4*)&geomall[tid][4] = gB;
    }

    // layer-1 bias C-in vectors: rows n = 4q..4q+3 (lo) and 16+4q.. (hi);
    // layer-2 bias: own channel only
    const f32x4 b1lo0 = *(const f32x4*)(b1_0 + 4 * q), b1hi0 = *(const f32x4*)(b1_0 + 16 + 4 * q);
    const f32x4 b1lo1 = *(const f32x4*)(b1_1 + 4 * q), b1hi1 = *(const f32x4*)(b1_1 + 16 + 4 * q);
    const f32x4 b1lo2 = *(const f32x4*)(b1_2 + 4 * q), b1hi2 = *(const f32x4*)(b1_2 + 16 + 4 * q);
    const f32x4 b1lo3 = *(const f32x4*)(b1_3 + 4 * q), b1hi3 = *(const f32x4*)(b1_3 + 16 + 4 * q);
    const f32x4 b1lo4 = *(const f32x4*)(b1_4 + 4 * q), b1hi4 = *(const f32x4*)(b1_4 + 16 + 4 * q);
    const float b2v0 = b2_0[cw], b2v1 = b2_1[cw], b2v2 = b2_2[cw];
    const float b2v3 = b2_3[cw], b2v4 = b2_4[cw];
    __syncthreads();

    // 21 named scalar accumulators
    float a0 = 0.f, a1 = 0.f, a2 = 0.f, a3 = 0.f, a4 = 0.f, a5 = 0.f, a6 = 0.f;
    float a7 = 0.f, a8 = 0.f, a9 = 0.f, a10 = 0.f, a11 = 0.f, a12 = 0.f, a13 = 0.f;
    float a14 = 0.f, a15 = 0.f, a16 = 0.f, a17 = 0.f, a18 = 0.f, a19 = 0.f, a20 = 0.f;

    const int pairb = (w >> 1) * 128;        // this wave-pair's b range

    // software prefetch of the first rbf fragment
    const float* rbase = rbf + (rowbase + pairb + ln) * 32 + q * 8;
    f32x4 curA = *(const f32x4*)rbase;
    f32x4 curB = *(const f32x4*)(rbase + 4);

    #pragma unroll 1
    for (int t = 0; t < 8; ++t) {
        const int b0 = pairb + t * 16;

        // convert current rbf fragment (packed), then prefetch next tile's
        union { bf16x8 v; unsigned u[4]; } ru;
        ru.u[0] = cvtpk(curA[0], curA[1]);
        ru.u[1] = cvtpk(curA[2], curA[3]);
        ru.u[2] = cvtpk(curB[0], curB[1]);
        ru.u[3] = cvtpk(curB[2], curB[3]);
        const bf16x8 rbfF = ru.v;
        if (t < 7) {
            curA = *(const f32x4*)(rbase + (t + 1) * 512);
            curB = *(const f32x4*)(rbase + (t + 1) * 512 + 4);
        }

        f32x4 rF0, rF1, rF2, rF3, rF4;
        MLP3S(0 * 64 * WS, b1lo0, b1hi0, b2v0, rF0)
        MLP3S(1 * 64 * WS, b1lo1, b1hi1, b2v1, rF1)
        MLP3S(2 * 64 * WS, b1lo2, b1hi2, b2v2, rF2)
        MLP3S(3 * 64 * WS, b1lo3, b1hi3, b2v3, rF3)
        MLP3S(4 * 64 * WS, b1lo4, b1hi4, b2v4, rF4)

        AGGM(0) AGGM(1) AGGM(2) AGGM(3)

        __builtin_amdgcn_sched_barrier(0);
    }

    // ---- reduce over q within wave, then over the 4 b-range pairs via LDS ----
    __syncthreads();                       // all waves done reading wlds
    float* red = (float*)wlds;             // [8][21][16] = 10752 B <= 25600 B
    RED(0,  a0)  RED(1,  a1)  RED(2,  a2)  RED(3,  a3)  RED(4,  a4)
    RED(5,  a5)  RED(6,  a6)  RED(7,  a7)  RED(8,  a8)  RED(9,  a9)
    RED(10, a10) RED(11, a11) RED(12, a12) RED(13, a13) RED(14, a14)
    RED(15, a15) RED(16, a16) RED(17, a17) RED(18, a18) RED(19, a19)
    RED(20, a20)
    __syncthreads();

    const int NC = NN * CC;
    for (int e = tid; e < 21 * 32; e += 512) {
        const int cmp = e >> 5, c = e & 31;
        const int hh = c >> 4, l2 = c & 15;
        float s = 0.f;
        #pragma unroll
        for (int p = 0; p < 4; ++p)
            s += red[((p * 2 + hh) * 21 + cmp) * 16 + l2];
        int idx;
        if (cmp == 0)       idx = a * CC + c;                                       // o0_s
        else if (cmp == 1)  idx = NC + a * CC + c;                                  // o0_b
        else if (cmp < 5)   idx = 2 * NC + (a * CC + c) * 3 + (cmp - 2);            // o1_a
        else if (cmp < 8)   idx = 2 * NC + 3 * NC + (a * CC + c) * 3 + (cmp - 5);   // o1_s
        else if (cmp < 11)  idx = 2 * NC + 6 * NC + (a * CC + c) * 3 + (cmp - 8);   // o1_c
        else if (cmp < 16)  idx = 11 * NC + (a * CC + c) * 5 + (cmp - 11);          // o2_a
        else                idx = 11 * NC + 5 * NC + (a * CC + c) * 5 + (cmp - 16); // o2_s
        out[idx] = s;
    }
}

extern "C" void kernel_launch(void* const* d_in, const int* in_sizes, int n_in,
                              void* d_out, int out_size, void* d_ws, size_t ws_size,
                              hipStream_t stream) {
    const float* in0 = (const float*)d_in[0];
    const float* in1 = (const float*)d_in[1];
    const float* in2 = (const float*)d_in[2];
    const float* rbf = (const float*)d_in[3];
    const float* rij = (const float*)d_in[4];

    hipLaunchKernelGGL(tfn_mfma, dim3(NN), dim3(512), 0, stream,
                       in0, in1, in2, rbf, rij,
                       (const float*)d_in[5],  (const float*)d_in[6],
                       (const float*)d_in[7],  (const float*)d_in[8],
                       (const float*)d_in[9],  (const float*)d_in[10],
                       (const float*)d_in[11], (const float*)d_in[12],
                       (const float*)d_in[13], (const float*)d_in[14],
                       (const float*)d_in[15], (const float*)d_in[16],
                       (const float*)d_in[17], (const float*)d_in[18],
                       (const float*)d_in[19], (const float*)d_in[20],
                       (const float*)d_in[21], (const float*)d_in[22],
                       (const float*)d_in[23], (const float*)d_in[24],
                       (float*)d_out);
}

// Round 13
// 35.429 us; speedup vs baseline: 2.9116x; 1.1420x over previous
//
#include <hip/hip_runtime.h>
#include <math.h>

#define NN 512
#define CC 32
#define EPSF 1e-8f
#define WS 40   // shorts per LDS row

typedef __attribute__((ext_vector_type(8))) short bf16x8;
typedef __attribute__((ext_vector_type(4))) float f32x4;

// fp32 -> bf16 bits, round-to-nearest-even (staging only)
__device__ __forceinline__ short f2bf(float f) {
    unsigned u = __float_as_uint(f);
    u += 0x7fffu + ((u >> 16) & 1u);
    return (short)(u >> 16);
}

// packed f32x2 -> bf16x2 (RTNE), 1 VALU op
__device__ __forceinline__ unsigned cvtpk(float lo, float hi) {
    unsigned r;
    asm("v_cvt_pk_bf16_f32 %0, %1, %2" : "=v"(r) : "v"(lo), "v"(hi));
    return r;
}

// Stage filter F's weights as bf16 into LDS (compile-time F).
// w1 stored plain: row n, col k.  w2 stored with k-axis permuted by perm()
// so layer-2's A-fragment is lane-local after the swapped layer-1 MFMA.
#define STAGE_F(F, W1P, W2P)                                                   \
    {                                                                          \
        wlds[(((F) * 2 + 0) * 32 + n0) * WS + k0]      = f2bf((W1P)[tid]);     \
        wlds[(((F) * 2 + 0) * 32 + n0 + 16) * WS + k0] = f2bf((W1P)[tid+512]); \
        wlds[(((F) * 2 + 1) * 32 + n0) * WS + k2]      = f2bf((W2P)[tid]);     \
        wlds[(((F) * 2 + 1) * 32 + n0 + 16) * WS + k2] = f2bf((W2P)[tid+512]); \
    }

// Radial MLP, transpose-free (w2 fragment pre-hoisted to registers):
//  layer1 swapped operands: d = mfma(w1, rbf) -> lane(q,ln) = h[n][p=ln]
//  relu+cvt_pk packs the 8 lane-local h values; under the k-permutation they
//  ARE the layer-2 A-frag (w2 staged with matching permutation)
//  layer2: R[rr] = rad[p=4q+rr][cw]
#define MLP3S(WOFF, B1LO, B1HI, B2V, W2F, R)                                       \
    {                                                                              \
        const bf16x8 w1loM = *(const bf16x8*)&wlds[(WOFF) + ln * WS + q * 8];      \
        const bf16x8 w1hiM = *(const bf16x8*)&wlds[(WOFF) + (16 + ln) * WS + q * 8]; \
        f32x4 d0M = (B1LO);                                                        \
        f32x4 d1M = (B1HI);                                                        \
        d0M = __builtin_amdgcn_mfma_f32_16x16x32_bf16(w1loM, rbfF, d0M, 0, 0, 0);  \
        d1M = __builtin_amdgcn_mfma_f32_16x16x32_bf16(w1hiM, rbfF, d1M, 0, 0, 0);  \
        union { bf16x8 v; unsigned u[4]; } hu;                                     \
        hu.u[0] = cvtpk(fmaxf(d0M[0], 0.f), fmaxf(d0M[1], 0.f));                   \
        hu.u[1] = cvtpk(fmaxf(d0M[2], 0.f), fmaxf(d0M[3], 0.f));                   \
        hu.u[2] = cvtpk(fmaxf(d1M[0], 0.f), fmaxf(d1M[1], 0.f));                   \
        hu.u[3] = cvtpk(fmaxf(d1M[2], 0.f), fmaxf(d1M[3], 0.f));                   \
        f32x4 eM = { (B2V), (B2V), (B2V), (B2V) };                                 \
        R = __builtin_amdgcn_mfma_f32_16x16x32_bf16(hu.v, (W2F), eM, 0, 0, 0);     \
    }

// Merged aggregation for pair slot rr: all 5 filters, deduped loads.
#define AGGM(RR)                                                               \
    {                                                                          \
        const int bA = b0 + q * 4 + (RR);                                      \
        const f32x4 gA = *(const f32x4*)&geomall[bA][0];                       \
        const f32x4 gB = *(const f32x4*)&geomall[bA][4];                       \
        const float i0A = in0[bA * CC + cw];                                   \
        const float* i1A = in1 + (bA * CC + cw) * 3;                           \
        const float x1A = i1A[0], y1A = i1A[1], z1A = i1A[2];                  \
        const float* i2A = in2 + (bA * CC + cw) * 5;                           \
        const float p0A = i2A[0], p1A = i2A[1], p2A = i2A[2];                  \
        const float p3A = i2A[3], p4A = i2A[4];                                \
        const float s0A = rF0[(RR)];                                           \
        a0  = fmaf(s0A, i0A, a0);                                              \
        a5  = fmaf(s0A, x1A, a5);                                              \
        a6  = fmaf(s0A, y1A, a6);                                              \
        a7  = fmaf(s0A, z1A, a7);                                              \
        a16 = fmaf(s0A, p0A, a16);                                             \
        a17 = fmaf(s0A, p1A, a17);                                             \
        a18 = fmaf(s0A, p2A, a18);                                             \
        a19 = fmaf(s0A, p3A, a19);                                             \
        a20 = fmaf(s0A, p4A, a20);                                             \
        const float t1A = rF1[(RR)] * i0A;                                     \
        a2  = fmaf(t1A, gA[0], a2);                                            \
        a3  = fmaf(t1A, gA[1], a3);                                            \
        a4  = fmaf(t1A, gA[2], a4);                                            \
        const float t2A = rF2[(RR)] * i0A;                                     \
        a11 = fmaf(t2A, gA[3], a11);                                           \
        a12 = fmaf(t2A, gB[0], a12);                                           \
        a13 = fmaf(t2A, gB[1], a13);                                           \
        a14 = fmaf(t2A, gB[2], a14);                                           \
        a15 = fmaf(t2A, gB[3], a15);                                           \
        const float dtA = fmaf(gA[2], z1A, fmaf(gA[1], y1A, gA[0] * x1A));     \
        a1  = fmaf(rF3[(RR)], dtA, a1);                                        \
        const float cxA = fmaf(gA[1], z1A, -(gA[2] * y1A));                    \
        const float cyA = fmaf(gA[2], x1A, -(gA[0] * z1A));                    \
        const float czA = fmaf(gA[0], y1A, -(gA[1] * x1A));                    \
        a8  = fmaf(rF4[(RR)], cxA, a8);                                        \
        a9  = fmaf(rF4[(RR)], cyA, a9);                                        \
        a10 = fmaf(rF4[(RR)], czA, a10);                                       \
    }

#define RED(CMP, V)                                                            \
    {                                                                          \
        float vR = (V);                                                        \
        vR += __shfl_down(vR, 32);                                             \
        vR += __shfl_down(vR, 16);                                             \
        if (lane < 16) red[(w * 21 + (CMP)) * 16 + ln] = vR;                   \
    }

__global__ __launch_bounds__(512, 2) void tfn_mfma(
    const float* __restrict__ in0,   // [N,C,1]
    const float* __restrict__ in1,   // [N,C,3]
    const float* __restrict__ in2,   // [N,C,5]
    const float* __restrict__ rbf,   // [N,N,32]
    const float* __restrict__ rij,   // [N,N,3]
    const float* __restrict__ w1_0, const float* __restrict__ b1_0,
    const float* __restrict__ w2_0, const float* __restrict__ b2_0,
    const float* __restrict__ w1_1, const float* __restrict__ b1_1,
    const float* __restrict__ w2_1, const float* __restrict__ b2_1,
    const float* __restrict__ w1_2, const float* __restrict__ b1_2,
    const float* __restrict__ w2_2, const float* __restrict__ b2_2,
    const float* __restrict__ w1_3, const float* __restrict__ b1_3,
    const float* __restrict__ w2_3, const float* __restrict__ b2_3,
    const float* __restrict__ w1_4, const float* __restrict__ b1_4,
    const float* __restrict__ w2_4, const float* __restrict__ b2_4,
    float* __restrict__ out)
{
    const int a    = blockIdx.x;
    const int tid  = threadIdx.x;
    const int w    = tid >> 6;     // wave 0..7 = (b-range pair) * 2 + channel-half
    const int lane = tid & 63;
    const int q    = lane >> 4;
    const int ln   = lane & 15;
    const int ch0  = (w & 1) * 16; // this wave's channel-half base
    const int cw   = ch0 + ln;     // this lane's channel

    __shared__ short wlds[5 * 2 * 32 * WS];  // 25600 B; aliased as `red` later
    __shared__ float geomall[NN][8];         // 16384 B: all b's geometry (mask folded)

    // staging indices; k2 = perm(k0): n-axis permutation for layer-2 weights
    const int n0 = tid >> 5, k0 = tid & 31;
    const int k2 = (k0 < 16) ? ((k0 >> 2) * 8 + (k0 & 3))
                             : (((k0 - 16) >> 2) * 8 + 4 + ((k0 - 16) & 3));

    STAGE_F(0, w1_0, w2_0)
    STAGE_F(1, w1_1, w2_1)
    STAGE_F(2, w1_2, w2_2)
    STAGE_F(3, w1_3, w2_3)
    STAGE_F(4, w1_4, w2_4)

    const size_t rowbase = (size_t)a * NN;
    const float Y2C = 0.28867513459481287f;  // 1/(2*sqrt(3))

    // ---- geometry for ALL 512 b's, one thread each (no divergence) ----
    {
        const float* rp = rij + (rowbase + tid) * 3;
        const float x = rp[0], y = rp[1], z = rp[2];
        const float d2 = x * x + y * y + z * z;
        const float d  = sqrtf(d2);
        const float m  = (d >= EPSF) ? 1.f : 0.f;
        const float inv = m / (d + EPSF);
        const float ir2 = m / fmaxf(d2, EPSF);
        f32x4 gA = { x * inv, y * inv, z * inv, x * y * ir2 };
        f32x4 gB = { y * z * ir2, (2.f * z * z - x * x - y * y) * (ir2 * Y2C),
                     z * x * ir2, (x * x - y * y) * (ir2 * 0.5f) };
        *(f32x4*)&geomall[tid][0] = gA;
        *(f32x4*)&geomall[tid][4] = gB;
    }

    // layer-1 bias C-in vectors; layer-2 bias: own channel only
    const f32x4 b1lo0 = *(const f32x4*)(b1_0 + 4 * q), b1hi0 = *(const f32x4*)(b1_0 + 16 + 4 * q);
    const f32x4 b1lo1 = *(const f32x4*)(b1_1 + 4 * q), b1hi1 = *(const f32x4*)(b1_1 + 16 + 4 * q);
    const f32x4 b1lo2 = *(const f32x4*)(b1_2 + 4 * q), b1hi2 = *(const f32x4*)(b1_2 + 16 + 4 * q);
    const f32x4 b1lo3 = *(const f32x4*)(b1_3 + 4 * q), b1hi3 = *(const f32x4*)(b1_3 + 16 + 4 * q);
    const f32x4 b1lo4 = *(const f32x4*)(b1_4 + 4 * q), b1hi4 = *(const f32x4*)(b1_4 + 16 + 4 * q);
    const float b2v0 = b2_0[cw], b2v1 = b2_1[cw], b2v2 = b2_2[cw];
    const float b2v3 = b2_3[cw], b2v4 = b2_4[cw];
    __syncthreads();

    // hoist loop-invariant layer-2 weight fragments into registers (20 VGPR)
    const bf16x8 w2F0 = *(const bf16x8*)&wlds[0 * 64 * WS + (32 + ch0 + ln) * WS + q * 8];
    const bf16x8 w2F1 = *(const bf16x8*)&wlds[1 * 64 * WS + (32 + ch0 + ln) * WS + q * 8];
    const bf16x8 w2F2 = *(const bf16x8*)&wlds[2 * 64 * WS + (32 + ch0 + ln) * WS + q * 8];
    const bf16x8 w2F3 = *(const bf16x8*)&wlds[3 * 64 * WS + (32 + ch0 + ln) * WS + q * 8];
    const bf16x8 w2F4 = *(const bf16x8*)&wlds[4 * 64 * WS + (32 + ch0 + ln) * WS + q * 8];

    // 21 named scalar accumulators
    float a0 = 0.f, a1 = 0.f, a2 = 0.f, a3 = 0.f, a4 = 0.f, a5 = 0.f, a6 = 0.f;
    float a7 = 0.f, a8 = 0.f, a9 = 0.f, a10 = 0.f, a11 = 0.f, a12 = 0.f, a13 = 0.f;
    float a14 = 0.f, a15 = 0.f, a16 = 0.f, a17 = 0.f, a18 = 0.f, a19 = 0.f, a20 = 0.f;

    const int pairb = (w >> 1) * 128;        // this wave-pair's b range

    // software prefetch of the first rbf fragment
    const float* rbase = rbf + (rowbase + pairb + ln) * 32 + q * 8;
    f32x4 curA = *(const f32x4*)rbase;
    f32x4 curB = *(const f32x4*)(rbase + 4);

    #pragma unroll 1
    for (int t = 0; t < 8; ++t) {
        const int b0 = pairb + t * 16;

        // convert current rbf fragment (packed), then prefetch next tile's
        union { bf16x8 v; unsigned u[4]; } ru;
        ru.u[0] = cvtpk(curA[0], curA[1]);
        ru.u[1] = cvtpk(curA[2], curA[3]);
        ru.u[2] = cvtpk(curB[0], curB[1]);
        ru.u[3] = cvtpk(curB[2], curB[3]);
        const bf16x8 rbfF = ru.v;
        if (t < 7) {
            curA = *(const f32x4*)(rbase + (t + 1) * 512);
            curB = *(const f32x4*)(rbase + (t + 1) * 512 + 4);
        }

        f32x4 rF0, rF1, rF2, rF3, rF4;
        MLP3S(0 * 64 * WS, b1lo0, b1hi0, b2v0, w2F0, rF0)
        MLP3S(1 * 64 * WS, b1lo1, b1hi1, b2v1, w2F1, rF1)
        MLP3S(2 * 64 * WS, b1lo2, b1hi2, b2v2, w2F2, rF2)
        MLP3S(3 * 64 * WS, b1lo3, b1hi3, b2v3, w2F3, rF3)
        MLP3S(4 * 64 * WS, b1lo4, b1hi4, b2v4, w2F4, rF4)

        AGGM(0) AGGM(1) AGGM(2) AGGM(3)
    }

    // ---- reduce over q within wave, then over the 4 b-range pairs via LDS ----
    __syncthreads();                       // all waves done reading wlds
    float* red = (float*)wlds;             // [8][21][16] = 10752 B <= 25600 B
    RED(0,  a0)  RED(1,  a1)  RED(2,  a2)  RED(3,  a3)  RED(4,  a4)
    RED(5,  a5)  RED(6,  a6)  RED(7,  a7)  RED(8,  a8)  RED(9,  a9)
    RED(10, a10) RED(11, a11) RED(12, a12) RED(13, a13) RED(14, a14)
    RED(15, a15) RED(16, a16) RED(17, a17) RED(18, a18) RED(19, a19)
    RED(20, a20)
    __syncthreads();

    const int NC = NN * CC;
    for (int e = tid; e < 21 * 32; e += 512) {
        const int cmp = e >> 5, c = e & 31;
        const int hh = c >> 4, l2 = c & 15;
        float s = 0.f;
        #pragma unroll
        for (int p = 0; p < 4; ++p)
            s += red[((p * 2 + hh) * 21 + cmp) * 16 + l2];
        int idx;
        if (cmp == 0)       idx = a * CC + c;                                       // o0_s
        else if (cmp == 1)  idx = NC + a * CC + c;                                  // o0_b
        else if (cmp < 5)   idx = 2 * NC + (a * CC + c) * 3 + (cmp - 2);            // o1_a
        else if (cmp < 8)   idx = 2 * NC + 3 * NC + (a * CC + c) * 3 + (cmp - 5);   // o1_s
        else if (cmp < 11)  idx = 2 * NC + 6 * NC + (a * CC + c) * 3 + (cmp - 8);   // o1_c
        else if (cmp < 16)  idx = 11 * NC + (a * CC + c) * 5 + (cmp - 11);          // o2_a
        else                idx = 11 * NC + 5 * NC + (a * CC + c) * 5 + (cmp - 16); // o2_s
        out[idx] = s;
    }
}

extern "C" void kernel_launch(void* const* d_in, const int* in_sizes, int n_in,
                              void* d_out, int out_size, void* d_ws, size_t ws_size,
                              hipStream_t stream) {
    const float* in0 = (const float*)d_in[0];
    const float* in1 = (const float*)d_in[1];
    const float* in2 = (const float*)d_in[2];
    const float* rbf = (const float*)d_in[3];
    const float* rij = (const float*)d_in[4];

    hipLaunchKernelGGL(tfn_mfma, dim3(NN), dim3(512), 0, stream,
                       in0, in1, in2, rbf, rij,
                       (const float*)d_in[5],  (const float*)d_in[6],
                       (const float*)d_in[7],  (const float*)d_in[8],
                       (const float*)d_in[9],  (const float*)d_in[10],
                       (const float*)d_in[11], (const float*)d_in[12],
                       (const float*)d_in[13], (const float*)d_in[14],
                       (const float*)d_in[15], (const float*)d_in[16],
                       (const float*)d_in[17], (const float*)d_in[18],
                       (const float*)d_in[19], (const float*)d_in[20],
                       (const float*)d_in[21], (const float*)d_in[22],
                       (const float*)d_in[23], (const float*)d_in[24],
                       (float*)d_out);
}